// Round 1
// baseline (1114.774 us; speedup 1.0000x reference)
//
#include <hip/hip_runtime.h>
#include <hip/hip_bf16.h>

// ARMANet: 2x ARMAConv(K=1,T=1) + global mean pool + FC
// N=100000 nodes, E=1600000 edges, IN=HID=64, OUT=32, G=64 graphs.

#define NODES_PER_GEMM_TILE 64
#define POOL_CHUNK 1024

// ---------------- degree / norm ----------------
__global__ void deg_kernel(const int* __restrict__ col, float* __restrict__ deg, int E) {
    int e = blockIdx.x * 256 + threadIdx.x;
    if (e < E) atomicAdd(&deg[col[e]], 1.0f);
}

__global__ void dinv_kernel(float* __restrict__ deg, int n) {
    int i = blockIdx.x * 256 + threadIdx.x;
    if (i < n) {
        float d = deg[i];
        deg[i] = (d > 0.0f) ? rsqrtf(d) : 0.0f;
    }
}

// ---------------- dual GEMM: T = X@W1, R = X@W2 + b ----------------
__global__ void gemm_dual(const float* __restrict__ X, const float* __restrict__ W1,
                          const float* __restrict__ W2, const float* __restrict__ b,
                          float* __restrict__ T, float* __restrict__ R, int n) {
    __shared__ float sW1[64 * 64];
    __shared__ float sW2[64 * 64];
    __shared__ float sX[64 * 64];
    int tid = threadIdx.x;  // 256 threads
    for (int i = tid; i < 4096; i += 256) {
        sW1[i] = W1[i];
        sW2[i] = W2[i];
    }
    int node0 = blockIdx.x * NODES_PER_GEMM_TILE;
    for (int i = tid; i < 4096; i += 256) {
        int r = i >> 6, c = i & 63;
        int node = node0 + r;
        sX[i] = (node < n) ? X[node * 64 + c] : 0.0f;
    }
    __syncthreads();
    int d = tid & 63;
    int i0 = tid >> 6;  // 0..3
    float bias = b[d];
    for (int i = i0; i < NODES_PER_GEMM_TILE; i += 4) {
        int node = node0 + i;
        if (node >= n) break;
        float acc1 = 0.0f, acc2 = 0.0f;
#pragma unroll
        for (int k = 0; k < 64; ++k) {
            float xv = sX[i * 64 + k];
            acc1 = fmaf(xv, sW1[k * 64 + d], acc1);
            acc2 = fmaf(xv, sW2[k * 64 + d], acc2);
        }
        T[node * 64 + d] = acc1;
        R[node * 64 + d] = acc2 + bias;
    }
}

// ---------------- propagate: AGG[col] += dinv[row]*dinv[col] * T[row] ----------------
__global__ void propagate(const float* __restrict__ T, const int* __restrict__ row,
                          const int* __restrict__ col, const float* __restrict__ dinv,
                          float* __restrict__ AGG, int E) {
    int e = blockIdx.x * 4 + (threadIdx.x >> 6);
    if (e >= E) return;
    int d = threadIdx.x & 63;
    int r = row[e];
    int c = col[e];
    float nrm = dinv[r] * dinv[c];
    atomicAdd(&AGG[c * 64 + d], nrm * T[r * 64 + d]);
}

// ---------------- elementwise relu(A+B) -> O ----------------
__global__ void relu_add(const float* __restrict__ A, const float* __restrict__ B,
                         float* __restrict__ O, int total) {
    int i = blockIdx.x * 256 + threadIdx.x;
    if (i < total) O[i] = fmaxf(A[i] + B[i], 0.0f);
}

// ---------------- relu(AGG+R) then pooled[batch] += h ; cnt[batch] += 1 ----------------
__global__ void relu_pool(const float* __restrict__ AGG, const float* __restrict__ Rr,
                          const int* __restrict__ batch, float* __restrict__ pooled,
                          float* __restrict__ cnt, int n) {
    __shared__ float sAcc[64 * 64];  // [graph][dim]
    __shared__ float sCnt[64];
    int tid = threadIdx.x;  // 256
    for (int i = tid; i < 4096; i += 256) sAcc[i] = 0.0f;
    if (tid < 64) sCnt[tid] = 0.0f;
    __syncthreads();
    int start = blockIdx.x * POOL_CHUNK;
    int end = min(start + POOL_CHUNK, n);
    int d = tid & 63;
    int i0 = tid >> 6;
    for (int i = start + i0; i < end; i += 4) {
        float v = AGG[i * 64 + d] + Rr[i * 64 + d];
        v = fmaxf(v, 0.0f);
        int g = batch[i];
        atomicAdd(&sAcc[g * 64 + d], v);
        if (d == 0) atomicAdd(&sCnt[g], 1.0f);
    }
    __syncthreads();
    for (int i = tid; i < 4096; i += 256) {
        float v = sAcc[i];
        if (v != 0.0f) atomicAdd(&pooled[i], v);
    }
    if (tid < 64) {
        float v = sCnt[tid];
        if (v != 0.0f) atomicAdd(&cnt[tid], v);
    }
}

// ---------------- out[g,o] = (pooled[g,:]/max(cnt,1)) @ fcw + fcb ----------------
__global__ void final_fc(const float* __restrict__ pooled, const float* __restrict__ cnt,
                         const float* __restrict__ fcw, const float* __restrict__ fcb,
                         float* __restrict__ out) {
    int idx = blockIdx.x * 256 + threadIdx.x;
    if (idx >= 64 * 32) return;
    int g = idx >> 5, o = idx & 31;
    float c = fmaxf(cnt[g], 1.0f);
    float acc = 0.0f;
#pragma unroll
    for (int k = 0; k < 64; ++k) acc = fmaf(pooled[g * 64 + k], fcw[k * 32 + o], acc);
    out[idx] = acc / c + fcb[o];
}

extern "C" void kernel_launch(void* const* d_in, const int* in_sizes, int n_in,
                              void* d_out, int out_size, void* d_ws, size_t ws_size,
                              hipStream_t stream) {
    const float* x       = (const float*)d_in[0];
    const int*   eidx    = (const int*)d_in[1];
    const int*   batch   = (const int*)d_in[2];
    const float* w1_init = (const float*)d_in[3];
    const float* w1_root = (const float*)d_in[4];
    const float* b1      = (const float*)d_in[5];
    const float* w2_init = (const float*)d_in[6];
    const float* w2_root = (const float*)d_in[7];
    const float* b2      = (const float*)d_in[8];
    const float* fc_w    = (const float*)d_in[9];
    const float* fc_b    = (const float*)d_in[10];
    float* out = (float*)d_out;

    const int N = in_sizes[0] / 64;
    const int E = in_sizes[1] / 2;
    const int* row = eidx;
    const int* col = eidx + E;

    // workspace layout (floats):
    // [dinv N][pooled 4096][cnt 64][bufA N*64][bufB N*64][bufC N*64]
    float* ws = (float*)d_ws;
    float* dinv   = ws;
    float* pooled = dinv + N;
    float* cnt    = pooled + 64 * 64;
    float* bufA   = cnt + 64;
    float* bufB   = bufA + (size_t)N * 64;
    float* bufC   = bufB + (size_t)N * 64;

    const size_t nodeFeatBytes = (size_t)N * 64 * sizeof(float);
    const int total = N * 64;

    // zero dinv+pooled+cnt (contiguous)
    hipMemsetAsync(dinv, 0, (size_t)(N + 64 * 64 + 64) * sizeof(float), stream);

    // degrees -> dinv
    deg_kernel<<<(E + 255) / 256, 256, 0, stream>>>(col, dinv, E);
    dinv_kernel<<<(N + 255) / 256, 256, 0, stream>>>(dinv, N);

    // layer 1: T=x@w1_init -> bufA ; R=x@w1_root+b1 -> bufB
    gemm_dual<<<(N + 63) / 64, 256, 0, stream>>>(x, w1_init, w1_root, b1, bufA, bufB, N);

    // agg1 -> bufC
    hipMemsetAsync(bufC, 0, nodeFeatBytes, stream);
    propagate<<<(E + 3) / 4, 256, 0, stream>>>(bufA, row, col, dinv, bufC, E);

    // h1 = relu(agg1 + r1) -> bufA
    relu_add<<<(total + 255) / 256, 256, 0, stream>>>(bufC, bufB, bufA, total);

    // layer 2: T=h1@w2_init -> bufB ; R=h1@w2_root+b2 -> bufC
    gemm_dual<<<(N + 63) / 64, 256, 0, stream>>>(bufA, w2_init, w2_root, b2, bufB, bufC, N);

    // agg2 -> bufA
    hipMemsetAsync(bufA, 0, nodeFeatBytes, stream);
    propagate<<<(E + 3) / 4, 256, 0, stream>>>(bufB, row, col, dinv, bufA, E);

    // h2 = relu(agg2 + r2); pooled sums + counts
    relu_pool<<<(N + POOL_CHUNK - 1) / POOL_CHUNK, 256, 0, stream>>>(bufA, bufC, batch, pooled, cnt, N);

    // final FC
    final_fc<<<(64 * 32 + 255) / 256, 256, 0, stream>>>(pooled, cnt, fc_w, fc_b, out);
}

// Round 2
// 714.182 us; speedup vs baseline: 1.5609x; 1.5609x over previous
//
#include <hip/hip_runtime.h>
#include <hip/hip_bf16.h>

// ARMANet: 2x ARMAConv(K=1,T=1) + global mean pool + FC
// N=100000 nodes, E=1600000 edges, IN=HID=64, OUT=32, G=64 graphs.
// R2: gather-based propagate via on-the-fly CSR (no f32 atomics), fused relu.

#define POOL_CHUNK 1024

// ---------------- int degree count ----------------
__global__ void deg_int_kernel(const int* __restrict__ col, int* __restrict__ degi, int E) {
    int e = blockIdx.x * 256 + threadIdx.x;
    if (e < E) atomicAdd(&degi[col[e]], 1);
}

__global__ void dinv_kernel(const int* __restrict__ degi, float* __restrict__ dinv, int n) {
    int i = blockIdx.x * 256 + threadIdx.x;
    if (i < n) {
        int d = degi[i];
        dinv[i] = (d > 0) ? rsqrtf((float)d) : 0.0f;
    }
}

// ---------------- 3-kernel exclusive scan over degi -> start ----------------
// level 1: per-block (1024 elems) sums
__global__ void scan_s1(const int* __restrict__ degi, int* __restrict__ partial, int n) {
    __shared__ int s[256];
    int b = blockIdx.x, t = threadIdx.x;
    int base = b * 1024 + t * 4;
    int sum = 0;
#pragma unroll
    for (int j = 0; j < 4; ++j) {
        int idx = base + j;
        if (idx < n) sum += degi[idx];
    }
    s[t] = sum;
    __syncthreads();
    for (int off = 128; off > 0; off >>= 1) {
        if (t < off) s[t] += s[t + off];
        __syncthreads();
    }
    if (t == 0) partial[b] = s[0];
}

// level 2: exclusive scan of block partials (nb <= 128), in place
__global__ void scan_s2(int* __restrict__ partial, int nb) {
    __shared__ int s[128];
    int t = threadIdx.x;  // 128 threads
    s[t] = (t < nb) ? partial[t] : 0;
    __syncthreads();
    for (int off = 1; off < 128; off <<= 1) {
        int x = (t >= off) ? s[t - off] : 0;
        __syncthreads();
        s[t] += x;
        __syncthreads();
    }
    int ex = (t > 0) ? s[t - 1] : 0;
    if (t < nb) partial[t] = ex;
}

// level 3: per-block exclusive scan + block offset -> start[]
__global__ void scan_s3(const int* __restrict__ degi, const int* __restrict__ partial,
                        int* __restrict__ start, int n) {
    __shared__ int s[256];
    int b = blockIdx.x, t = threadIdx.x;
    int base = b * 1024 + t * 4;
    int v[4];
    int sum = 0;
#pragma unroll
    for (int j = 0; j < 4; ++j) {
        int idx = base + j;
        v[j] = (idx < n) ? degi[idx] : 0;
        sum += v[j];
    }
    s[t] = sum;
    __syncthreads();
    for (int off = 1; off < 256; off <<= 1) {
        int x = (t >= off) ? s[t - off] : 0;
        __syncthreads();
        s[t] += x;
        __syncthreads();
    }
    int excl = (t > 0) ? s[t - 1] : 0;
    int run = partial[b] + excl;
#pragma unroll
    for (int j = 0; j < 4; ++j) {
        int idx = base + j;
        if (idx < n) start[idx] = run;
        run += v[j];
    }
}

// ---------------- scatter edges into CSR slots ----------------
__global__ void scatter_kernel(const int* __restrict__ row, const int* __restrict__ col,
                               const int* __restrict__ start, int* __restrict__ cursor,
                               int* __restrict__ edge_src, int E) {
    int e = blockIdx.x * 256 + threadIdx.x;
    if (e < E) {
        int c = col[e];
        int p = start[c] + atomicAdd(&cursor[c], 1);
        edge_src[p] = row[e];
    }
}

// ---------------- dual GEMM: T = X@W1, R = X@W2 + b ----------------
__global__ void gemm_dual(const float* __restrict__ X, const float* __restrict__ W1,
                          const float* __restrict__ W2, const float* __restrict__ b,
                          float* __restrict__ T, float* __restrict__ R, int n) {
    __shared__ float sW1[64 * 64];
    __shared__ float sW2[64 * 64];
    __shared__ float sX[64 * 64];
    int tid = threadIdx.x;  // 256 threads
    for (int i = tid; i < 4096; i += 256) {
        sW1[i] = W1[i];
        sW2[i] = W2[i];
    }
    int node0 = blockIdx.x * 64;
    for (int i = tid; i < 4096; i += 256) {
        int r = i >> 6, c = i & 63;
        int node = node0 + r;
        sX[i] = (node < n) ? X[node * 64 + c] : 0.0f;
    }
    __syncthreads();
    int d = tid & 63;
    int i0 = tid >> 6;  // 0..3
    float bias = b[d];
    for (int i = i0; i < 64; i += 4) {
        int node = node0 + i;
        if (node >= n) break;
        float acc1 = 0.0f, acc2 = 0.0f;
#pragma unroll
        for (int k = 0; k < 64; ++k) {
            float xv = sX[i * 64 + k];
            acc1 = fmaf(xv, sW1[k * 64 + d], acc1);
            acc2 = fmaf(xv, sW2[k * 64 + d], acc2);
        }
        T[node * 64 + d] = acc1;
        R[node * 64 + d] = acc2 + bias;
    }
}

// ---------------- fused gather-propagate + relu ----------------
// H[c,:] = relu( sum_{e: col=c} dinv[row]*dinv[c] * T[row,:] + R[c,:] )
__global__ void gather_fused(const float* __restrict__ T, const float* __restrict__ R,
                             const int* __restrict__ edge_src, const int* __restrict__ start,
                             const int* __restrict__ degi, const float* __restrict__ dinv,
                             float* __restrict__ H, int n) {
    int c = blockIdx.x * 4 + (threadIdx.x >> 6);
    if (c >= n) return;
    int d = threadIdx.x & 63;
    int deg = degi[c];
    int s0 = start[c];
    float dc = dinv[c];
    float acc = 0.0f;
    for (int base = 0; base < deg; base += 64) {
        int m = min(deg - base, 64);
        int sid = 0;
        float w = 0.0f;
        if (d < m) {
            sid = edge_src[s0 + base + d];
            w = dinv[sid];
        }
        for (int j = 0; j < m; ++j) {
            int r = __shfl(sid, j);
            float nw = __shfl(w, j) * dc;
            acc = fmaf(nw, T[r * 64 + d], acc);
        }
    }
    float h = acc + R[c * 64 + d];
    H[c * 64 + d] = fmaxf(h, 0.0f);
}

// ---------------- pooled[batch] += h ; cnt[batch] += 1 ----------------
__global__ void pool_kernel(const float* __restrict__ Hin, const int* __restrict__ batch,
                            float* __restrict__ pooled, float* __restrict__ cnt, int n) {
    __shared__ float sAcc[64 * 64];  // [graph][dim]
    __shared__ float sCnt[64];
    int tid = threadIdx.x;  // 256
    for (int i = tid; i < 4096; i += 256) sAcc[i] = 0.0f;
    if (tid < 64) sCnt[tid] = 0.0f;
    __syncthreads();
    int s = blockIdx.x * POOL_CHUNK;
    int e = min(s + POOL_CHUNK, n);
    int d = tid & 63;
    int i0 = tid >> 6;
    for (int i = s + i0; i < e; i += 4) {
        float v = Hin[i * 64 + d];
        int g = batch[i];
        atomicAdd(&sAcc[g * 64 + d], v);
        if (d == 0) atomicAdd(&sCnt[g], 1.0f);
    }
    __syncthreads();
    for (int i = tid; i < 4096; i += 256) {
        float v = sAcc[i];
        if (v != 0.0f) atomicAdd(&pooled[i], v);
    }
    if (tid < 64) {
        float v = sCnt[tid];
        if (v != 0.0f) atomicAdd(&cnt[tid], v);
    }
}

// ---------------- out[g,o] = (pooled[g,:]/max(cnt,1)) @ fcw + fcb ----------------
__global__ void final_fc(const float* __restrict__ pooled, const float* __restrict__ cnt,
                         const float* __restrict__ fcw, const float* __restrict__ fcb,
                         float* __restrict__ out) {
    int idx = blockIdx.x * 256 + threadIdx.x;
    if (idx >= 64 * 32) return;
    int g = idx >> 5, o = idx & 31;
    float c = fmaxf(cnt[g], 1.0f);
    float acc = 0.0f;
#pragma unroll
    for (int k = 0; k < 64; ++k) acc = fmaf(pooled[g * 64 + k], fcw[k * 32 + o], acc);
    out[idx] = acc / c + fcb[o];
}

extern "C" void kernel_launch(void* const* d_in, const int* in_sizes, int n_in,
                              void* d_out, int out_size, void* d_ws, size_t ws_size,
                              hipStream_t stream) {
    const float* x       = (const float*)d_in[0];
    const int*   eidx    = (const int*)d_in[1];
    const int*   batch   = (const int*)d_in[2];
    const float* w1_init = (const float*)d_in[3];
    const float* w1_root = (const float*)d_in[4];
    const float* b1      = (const float*)d_in[5];
    const float* w2_init = (const float*)d_in[6];
    const float* w2_root = (const float*)d_in[7];
    const float* b2      = (const float*)d_in[8];
    const float* fc_w    = (const float*)d_in[9];
    const float* fc_b    = (const float*)d_in[10];
    float* out = (float*)d_out;

    const int N = in_sizes[0] / 64;
    const int E = in_sizes[1] / 2;
    const int* row = eidx;
    const int* col = eidx + E;

    // workspace layout
    float* ws = (float*)d_ws;
    float* dinv   = ws;                          // N
    float* pooled = dinv + N;                    // 4096
    float* cnt    = pooled + 64 * 64;            // 64
    float* bufA   = cnt + 64;                    // N*64
    float* bufB   = bufA + (size_t)N * 64;       // N*64
    float* bufC   = bufB + (size_t)N * 64;       // N*64
    int*   degi     = (int*)(bufC + (size_t)N * 64);  // N
    int*   start    = degi + N;                  // N
    int*   cursor   = start + N;                 // N
    int*   partial  = cursor + N;                // 128
    int*   edge_src = partial + 128;             // E

    const int nScanBlocks = (N + 1023) / 1024;   // 98 for N=100000 (must be <=128)

    // zero: degi/start/cursor (3N ints) ; pooled+cnt (4160 floats)
    hipMemsetAsync(degi, 0, (size_t)3 * N * sizeof(int), stream);
    hipMemsetAsync(pooled, 0, (size_t)(64 * 64 + 64) * sizeof(float), stream);

    // degrees / norm / CSR
    deg_int_kernel<<<(E + 255) / 256, 256, 0, stream>>>(col, degi, E);
    dinv_kernel<<<(N + 255) / 256, 256, 0, stream>>>(degi, dinv, N);
    scan_s1<<<nScanBlocks, 256, 0, stream>>>(degi, partial, N);
    scan_s2<<<1, 128, 0, stream>>>(partial, nScanBlocks);
    scan_s3<<<nScanBlocks, 256, 0, stream>>>(degi, partial, start, N);
    scatter_kernel<<<(E + 255) / 256, 256, 0, stream>>>(row, col, start, cursor, edge_src, E);

    // layer 1: T=x@w1_init -> bufA ; R=x@w1_root+b1 -> bufB
    gemm_dual<<<(N + 63) / 64, 256, 0, stream>>>(x, w1_init, w1_root, b1, bufA, bufB, N);
    // h1 = relu(prop(T) + R) -> bufC
    gather_fused<<<(N + 3) / 4, 256, 0, stream>>>(bufA, bufB, edge_src, start, degi, dinv, bufC, N);

    // layer 2
    gemm_dual<<<(N + 63) / 64, 256, 0, stream>>>(bufC, w2_init, w2_root, b2, bufA, bufB, N);
    gather_fused<<<(N + 3) / 4, 256, 0, stream>>>(bufA, bufB, edge_src, start, degi, dinv, bufC, N);

    // pool + FC
    pool_kernel<<<(N + POOL_CHUNK - 1) / POOL_CHUNK, 256, 0, stream>>>(bufC, batch, pooled, cnt, N);
    final_fc<<<(64 * 32 + 255) / 256, 256, 0, stream>>>(pooled, cnt, fc_w, fc_b, out);
}